// Round 1
// baseline (6209.808 us; speedup 1.0000x reference)
//
#include <hip/hip_runtime.h>
#include <math.h>

#define NN 100000
#define DH 128
#define DOUT 64

// ---------------------------------------------------------------------------
// Edge-index dtype detector: reference declares int64 but harness doc says
// int32. Interpreting genuine int32 pairs as int64 yields values >= 2^32 for
// any nonzero odd entry, so "first 1024 int64 values all in [0,N)" is a
// reliable int64 signature. Flag read by all edge kernels (wave-uniform).
// ---------------------------------------------------------------------------
__global__ __launch_bounds__(256) void detect_kernel(const int* __restrict__ ei, int E,
                                                     int* __restrict__ flag) {
  const long long* e64 = (const long long*)ei;
  int lim = E < 1024 ? E : 1024;
  int ok = 1;
  for (int i = threadIdx.x; i < lim; i += 256) {
    long long v = e64[i];
    if (v < 0 || v >= NN) ok = 0;
  }
  __shared__ int s_ok;
  if (threadIdx.x == 0) s_ok = 1;
  __syncthreads();
  if (!ok) atomicAnd(&s_ok, 0);
  __syncthreads();
  if (threadIdx.x == 0) *flag = s_ok;
}

__device__ __forceinline__ int edge_at(const int* __restrict__ ei, int is64, size_t pos) {
  return is64 ? (int)(((const long long*)ei)[pos]) : ei[pos];
}

// ---------------------------------------------------------------------------
// In-degree count (float so it can divide directly).
// ---------------------------------------------------------------------------
__global__ __launch_bounds__(256) void deg_kernel(const int* __restrict__ ei, int E,
                                                  const int* __restrict__ flag,
                                                  float* __restrict__ deg) {
  int e = blockIdx.x * 256 + threadIdx.x;
  if (e >= E) return;
  int is64 = *flag;
  int dst = edge_at(ei, is64, (size_t)E + e);
  atomicAdd(&deg[dst], 1.0f);
}

// ---------------------------------------------------------------------------
// Edge-parallel scatter-add: 32 threads per edge, float4 per thread.
// ---------------------------------------------------------------------------
__global__ __launch_bounds__(256) void scatter_kernel(const int* __restrict__ ei, int E,
                                                      const int* __restrict__ flag,
                                                      const float* __restrict__ feat,
                                                      float* __restrict__ s) {
  int tid = blockIdx.x * 256 + threadIdx.x;
  int e = tid >> 5;
  if (e >= E) return;
  int g = tid & 31;
  int is64 = *flag;
  int src = edge_at(ei, is64, (size_t)e);
  int dst = edge_at(ei, is64, (size_t)E + e);
  float4 v = ((const float4*)(feat + (size_t)src * DH))[g];
  float* o = s + (size_t)dst * DH + g * 4;
  atomicAdd(o + 0, v.x);
  atomicAdd(o + 1, v.y);
  atomicAdd(o + 2, v.z);
  atomicAdd(o + 3, v.w);
}

// ---------------------------------------------------------------------------
// Layer 1: h[n][j] = b1[j] + (s[n]/max(deg,1)) . W1l[j] + x[n] . W1r[j]
// 128 threads (one per output col), 4 nodes per block; rows staged in LDS,
// W rows streamed from L2 (amortized 4x by node blocking).
// ---------------------------------------------------------------------------
__global__ __launch_bounds__(128) void gemm1_kernel(const float* __restrict__ s,
                                                    const float* __restrict__ x,
                                                    const float* __restrict__ deg,
                                                    const float* __restrict__ W1l,
                                                    const float* __restrict__ b1l,
                                                    const float* __restrict__ W1r,
                                                    float* __restrict__ h) {
  __shared__ float sA[4][DH];
  __shared__ float sX[4][DH];
  int n0 = blockIdx.x * 4;
  int j = threadIdx.x;
#pragma unroll
  for (int n = 0; n < 4; n++) {
    float inv = 1.0f / fmaxf(deg[n0 + n], 1.0f);
    sA[n][j] = s[(size_t)(n0 + n) * DH + j] * inv;
    sX[n][j] = x[(size_t)(n0 + n) * DH + j];
  }
  __syncthreads();
  float acc0, acc1, acc2, acc3;
  acc0 = acc1 = acc2 = acc3 = b1l[j];
  const float4* wl4 = (const float4*)(W1l + (size_t)j * DH);
  const float4* wr4 = (const float4*)(W1r + (size_t)j * DH);
  const float4* a0 = (const float4*)sA[0];
  const float4* a1 = (const float4*)sA[1];
  const float4* a2 = (const float4*)sA[2];
  const float4* a3 = (const float4*)sA[3];
  const float4* x0 = (const float4*)sX[0];
  const float4* x1 = (const float4*)sX[1];
  const float4* x2 = (const float4*)sX[2];
  const float4* x3 = (const float4*)sX[3];
#pragma unroll 8
  for (int k = 0; k < DH / 4; k++) {
    float4 wl = wl4[k];
    float4 wr = wr4[k];
    float4 a, xr;
    a = a0[k]; xr = x0[k];
    acc0 += a.x * wl.x + a.y * wl.y + a.z * wl.z + a.w * wl.w
          + xr.x * wr.x + xr.y * wr.y + xr.z * wr.z + xr.w * wr.w;
    a = a1[k]; xr = x1[k];
    acc1 += a.x * wl.x + a.y * wl.y + a.z * wl.z + a.w * wl.w
          + xr.x * wr.x + xr.y * wr.y + xr.z * wr.z + xr.w * wr.w;
    a = a2[k]; xr = x2[k];
    acc2 += a.x * wl.x + a.y * wl.y + a.z * wl.z + a.w * wl.w
          + xr.x * wr.x + xr.y * wr.y + xr.z * wr.z + xr.w * wr.w;
    a = a3[k]; xr = x3[k];
    acc3 += a.x * wl.x + a.y * wl.y + a.z * wl.z + a.w * wl.w
          + xr.x * wr.x + xr.y * wr.y + xr.z * wr.z + xr.w * wr.w;
  }
  h[(size_t)(n0 + 0) * DH + j] = acc0;
  h[(size_t)(n0 + 1) * DH + j] = acc1;
  h[(size_t)(n0 + 2) * DH + j] = acc2;
  h[(size_t)(n0 + 3) * DH + j] = acc3;
}

// ---------------------------------------------------------------------------
// BN column stats: per-thread strided partial sums, then 2 atomics/thread.
// ---------------------------------------------------------------------------
__global__ __launch_bounds__(256) void bn_stats_kernel(const float* __restrict__ h,
                                                       float* __restrict__ sums,
                                                       float* __restrict__ sumsq) {
  int tid = blockIdx.x * 256 + threadIdx.x;
  int c = tid & (DH - 1);
  int r = tid >> 7;
  int stride = (gridDim.x * 256) >> 7;
  float sv = 0.0f, qv = 0.0f;
  for (; r < NN; r += stride) {
    float v = h[(size_t)r * DH + c];
    sv += v;
    qv += v * v;
  }
  atomicAdd(&sums[c], sv);
  atomicAdd(&sumsq[c], qv);
}

// BN scale/shift + ReLU, in place.
__global__ __launch_bounds__(256) void bn_apply_kernel(float* __restrict__ h,
                                                       const float* __restrict__ sums,
                                                       const float* __restrict__ sumsq,
                                                       const float* __restrict__ gamma,
                                                       const float* __restrict__ beta) {
  int tid = blockIdx.x * 256 + threadIdx.x;
  int c = tid & (DH - 1);
  float mean = sums[c] * (1.0f / NN);
  float var = sumsq[c] * (1.0f / NN) - mean * mean;
  float scl = gamma[c] * rsqrtf(var + 1e-5f);
  float sh = beta[c] - mean * scl;
  float v = h[tid] * scl + sh;
  h[tid] = fmaxf(v, 0.0f);
}

// ---------------------------------------------------------------------------
// Layer 2 + fused log_softmax. 64 threads (= 1 wave = all output cols),
// 4 nodes per block. Row-wise max/sumexp via wave-64 shuffles.
// ---------------------------------------------------------------------------
__global__ __launch_bounds__(64) void gemm2_kernel(const float* __restrict__ s,
                                                   const float* __restrict__ h,
                                                   const float* __restrict__ deg,
                                                   const float* __restrict__ W2l,
                                                   const float* __restrict__ b2l,
                                                   const float* __restrict__ W2r,
                                                   float* __restrict__ out) {
  __shared__ float sA[4][DH];
  __shared__ float sH[4][DH];
  int n0 = blockIdx.x * 4;
  int j = threadIdx.x;  // 0..63
#pragma unroll
  for (int n = 0; n < 4; n++) {
    float inv = 1.0f / fmaxf(deg[n0 + n], 1.0f);
    sA[n][j] = s[(size_t)(n0 + n) * DH + j] * inv;
    sA[n][j + 64] = s[(size_t)(n0 + n) * DH + j + 64] * inv;
    sH[n][j] = h[(size_t)(n0 + n) * DH + j];
    sH[n][j + 64] = h[(size_t)(n0 + n) * DH + j + 64];
  }
  __syncthreads();
  float acc[4];
  float b = b2l[j];
  acc[0] = acc[1] = acc[2] = acc[3] = b;
  const float4* wl4 = (const float4*)(W2l + (size_t)j * DH);
  const float4* wr4 = (const float4*)(W2r + (size_t)j * DH);
#pragma unroll 8
  for (int k = 0; k < DH / 4; k++) {
    float4 wl = wl4[k];
    float4 wr = wr4[k];
#pragma unroll
    for (int n = 0; n < 4; n++) {
      float4 a = ((const float4*)sA[n])[k];
      float4 hh = ((const float4*)sH[n])[k];
      acc[n] += a.x * wl.x + a.y * wl.y + a.z * wl.z + a.w * wl.w
              + hh.x * wr.x + hh.y * wr.y + hh.z * wr.z + hh.w * wr.w;
    }
  }
#pragma unroll
  for (int n = 0; n < 4; n++) {
    float m = acc[n];
    for (int o = 32; o > 0; o >>= 1) m = fmaxf(m, __shfl_xor(m, o, 64));
    float ev = __expf(acc[n] - m);
    float ssum = ev;
    for (int o = 32; o > 0; o >>= 1) ssum += __shfl_xor(ssum, o, 64);
    out[(size_t)(n0 + n) * DOUT + j] = acc[n] - m - logf(ssum);
  }
}

// ---------------------------------------------------------------------------
extern "C" void kernel_launch(void* const* d_in, const int* in_sizes, int n_in,
                              void* d_out, int out_size, void* d_ws, size_t ws_size,
                              hipStream_t stream) {
  const float* x = (const float*)d_in[0];
  const int* ei = (const int*)d_in[1];
  const float* W1l = (const float*)d_in[2];
  const float* b1l = (const float*)d_in[3];
  const float* W1r = (const float*)d_in[4];
  const float* gamma = (const float*)d_in[5];
  const float* beta = (const float*)d_in[6];
  const float* W2l = (const float*)d_in[7];
  const float* b2l = (const float*)d_in[8];
  const float* W2r = (const float*)d_in[9];
  float* out = (float*)d_out;
  int E = in_sizes[1] / 2;

  // workspace layout (floats): s_buf[N*128] | h_buf[N*128] | deg[N] | sums[128]
  //                            | sumsq[128] | flag[1]      (~103 MB total)
  float* s_buf = (float*)d_ws;
  float* h_buf = s_buf + (size_t)NN * DH;
  float* deg = h_buf + (size_t)NN * DH;
  float* sums = deg + NN;
  float* sumsq = sums + DH;
  int* flag = (int*)(sumsq + DH);

  hipMemsetAsync(s_buf, 0, (size_t)NN * DH * sizeof(float), stream);
  hipMemsetAsync(deg, 0, (size_t)(NN + 2 * DH) * sizeof(float), stream);

  detect_kernel<<<1, 256, 0, stream>>>(ei, E, flag);
  deg_kernel<<<(E + 255) / 256, 256, 0, stream>>>(ei, E, flag, deg);
  scatter_kernel<<<(E * 32 + 255) / 256, 256, 0, stream>>>(ei, E, flag, x, s_buf);
  gemm1_kernel<<<NN / 4, 128, 0, stream>>>(s_buf, x, deg, W1l, b1l, W1r, h_buf);
  bn_stats_kernel<<<512, 256, 0, stream>>>(h_buf, sums, sumsq);
  bn_apply_kernel<<<(NN * DH) / 256, 256, 0, stream>>>(h_buf, sums, sumsq, gamma, beta);
  hipMemsetAsync(s_buf, 0, (size_t)NN * DH * sizeof(float), stream);
  scatter_kernel<<<(E * 32 + 255) / 256, 256, 0, stream>>>(ei, E, flag, h_buf, s_buf);
  gemm2_kernel<<<NN / 4, 64, 0, stream>>>(s_buf, h_buf, deg, W2l, b2l, W2r, out);
}

// Round 2
// 1214.415 us; speedup vs baseline: 5.1134x; 5.1134x over previous
//
#include <hip/hip_runtime.h>
#include <math.h>

#define NN 100000
#define DH 128
#define DOUT 64

// ---------------------------------------------------------------------------
// Edge-index dtype detector (int64 reference vs int32 harness doc).
// ---------------------------------------------------------------------------
__global__ __launch_bounds__(256) void detect_kernel(const int* __restrict__ ei, int E,
                                                     int* __restrict__ flag) {
  const long long* e64 = (const long long*)ei;
  int lim = E < 1024 ? E : 1024;
  int ok = 1;
  for (int i = threadIdx.x; i < lim; i += 256) {
    long long v = e64[i];
    if (v < 0 || v >= NN) ok = 0;
  }
  __shared__ int s_ok;
  if (threadIdx.x == 0) s_ok = 1;
  __syncthreads();
  if (!ok) atomicAnd(&s_ok, 0);
  __syncthreads();
  if (threadIdx.x == 0) *flag = s_ok;
}

__device__ __forceinline__ int edge_at(const int* __restrict__ ei, int is64, size_t pos) {
  return is64 ? (int)(((const long long*)ei)[pos]) : ei[pos];
}

// ---------------------------------------------------------------------------
// In-degree histogram (int atomics: 1.6M ops, cheap).
// ---------------------------------------------------------------------------
__global__ __launch_bounds__(256) void deg_kernel(const int* __restrict__ ei, int E,
                                                  const int* __restrict__ flag,
                                                  int* __restrict__ degi) {
  int e = blockIdx.x * 256 + threadIdx.x;
  if (e >= E) return;
  int is64 = *flag;
  int dst = edge_at(ei, is64, (size_t)E + e);
  atomicAdd(&degi[dst], 1);
}

// ---------------------------------------------------------------------------
// Exclusive scan of degi -> row_ptr. Single block, 1024 threads, chunked.
// ---------------------------------------------------------------------------
__global__ __launch_bounds__(1024) void scan_kernel(const int* __restrict__ degi,
                                                    int* __restrict__ row_ptr) {
  __shared__ int warp_sums[16];
  __shared__ int s_offset;
  int lane = threadIdx.x & 63;
  int wid = threadIdx.x >> 6;
  if (threadIdx.x == 0) s_offset = 0;
  __syncthreads();
  for (int base = 0; base < NN; base += 1024) {
    int i = base + threadIdx.x;
    int v = (i < NN) ? degi[i] : 0;
    int sv = v;  // inclusive wave scan
#pragma unroll
    for (int o = 1; o < 64; o <<= 1) {
      int t = __shfl_up(sv, o, 64);
      if (lane >= o) sv += t;
    }
    if (lane == 63) warp_sums[wid] = sv;
    __syncthreads();
    if (wid == 0 && lane < 16) {
      int ws = warp_sums[lane];
#pragma unroll
      for (int o = 1; o < 16; o <<= 1) {
        int t = __shfl_up(ws, o, 16);
        if (lane >= o) ws += t;
      }
      warp_sums[lane] = ws;
    }
    __syncthreads();
    int wave_off = (wid == 0) ? 0 : warp_sums[wid - 1];
    int excl = s_offset + wave_off + sv - v;
    if (i < NN) row_ptr[i] = excl;
    __syncthreads();
    if (threadIdx.x == 1023) s_offset = excl + v;
    __syncthreads();
  }
}

// ---------------------------------------------------------------------------
// CSR fill. row_ptr doubles as the cursor: atomicAdd returns the absolute
// slot; afterwards row_ptr[n] == start[n] + deg[n], so start = row_ptr - deg.
// ---------------------------------------------------------------------------
__global__ __launch_bounds__(256) void fill_kernel(const int* __restrict__ ei, int E,
                                                   const int* __restrict__ flag,
                                                   int* __restrict__ row_ptr,
                                                   int* __restrict__ col) {
  int e = blockIdx.x * 256 + threadIdx.x;
  if (e >= E) return;
  int is64 = *flag;
  int src = edge_at(ei, is64, (size_t)e);
  int dst = edge_at(ei, is64, (size_t)E + e);
  int pos = atomicAdd(&row_ptr[dst], 1);
  col[pos] = src;
}

// ---------------------------------------------------------------------------
// Gather-based mean aggregation: 32 lanes per node, float4 per lane,
// accumulate in registers, single normalized write. No atomics.
// ---------------------------------------------------------------------------
__global__ __launch_bounds__(256) void gather_kernel(const float* __restrict__ feat,
                                                     const int* __restrict__ col,
                                                     const int* __restrict__ row_end,
                                                     const int* __restrict__ degi,
                                                     float* __restrict__ outp) {
  int tid = blockIdx.x * 256 + threadIdx.x;
  int n = tid >> 5;
  if (n >= NN) return;
  int g = tid & 31;
  int d = degi[n];
  int start = row_end[n] - d;  // row_ptr was advanced to end by fill_kernel
  float4 acc = make_float4(0.f, 0.f, 0.f, 0.f);
#pragma unroll 4
  for (int i = 0; i < d; i++) {
    int src = col[start + i];  // same addr across group -> broadcast
    float4 v = ((const float4*)(feat + (size_t)src * DH))[g];
    acc.x += v.x; acc.y += v.y; acc.z += v.z; acc.w += v.w;
  }
  float inv = 1.0f / (float)max(d, 1);
  ((float4*)(outp + (size_t)n * DH))[g] =
      make_float4(acc.x * inv, acc.y * inv, acc.z * inv, acc.w * inv);
}

// ---------------------------------------------------------------------------
// Layer 1: h[n][j] = b1[j] + s[n].W1l[j] + x[n].W1r[j]   (s pre-normalized)
// ---------------------------------------------------------------------------
__global__ __launch_bounds__(128) void gemm1_kernel(const float* __restrict__ s,
                                                    const float* __restrict__ x,
                                                    const float* __restrict__ W1l,
                                                    const float* __restrict__ b1l,
                                                    const float* __restrict__ W1r,
                                                    float* __restrict__ h) {
  __shared__ float sA[4][DH];
  __shared__ float sX[4][DH];
  int n0 = blockIdx.x * 4;
  int j = threadIdx.x;
#pragma unroll
  for (int n = 0; n < 4; n++) {
    sA[n][j] = s[(size_t)(n0 + n) * DH + j];
    sX[n][j] = x[(size_t)(n0 + n) * DH + j];
  }
  __syncthreads();
  float acc0, acc1, acc2, acc3;
  acc0 = acc1 = acc2 = acc3 = b1l[j];
  const float4* wl4 = (const float4*)(W1l + (size_t)j * DH);
  const float4* wr4 = (const float4*)(W1r + (size_t)j * DH);
  const float4* a0 = (const float4*)sA[0];
  const float4* a1 = (const float4*)sA[1];
  const float4* a2 = (const float4*)sA[2];
  const float4* a3 = (const float4*)sA[3];
  const float4* x0 = (const float4*)sX[0];
  const float4* x1 = (const float4*)sX[1];
  const float4* x2 = (const float4*)sX[2];
  const float4* x3 = (const float4*)sX[3];
#pragma unroll 8
  for (int k = 0; k < DH / 4; k++) {
    float4 wl = wl4[k];
    float4 wr = wr4[k];
    float4 a, xr;
    a = a0[k]; xr = x0[k];
    acc0 += a.x * wl.x + a.y * wl.y + a.z * wl.z + a.w * wl.w
          + xr.x * wr.x + xr.y * wr.y + xr.z * wr.z + xr.w * wr.w;
    a = a1[k]; xr = x1[k];
    acc1 += a.x * wl.x + a.y * wl.y + a.z * wl.z + a.w * wl.w
          + xr.x * wr.x + xr.y * wr.y + xr.z * wr.z + xr.w * wr.w;
    a = a2[k]; xr = x2[k];
    acc2 += a.x * wl.x + a.y * wl.y + a.z * wl.z + a.w * wl.w
          + xr.x * wr.x + xr.y * wr.y + xr.z * wr.z + xr.w * wr.w;
    a = a3[k]; xr = x3[k];
    acc3 += a.x * wl.x + a.y * wl.y + a.z * wl.z + a.w * wl.w
          + xr.x * wr.x + xr.y * wr.y + xr.z * wr.z + xr.w * wr.w;
  }
  h[(size_t)(n0 + 0) * DH + j] = acc0;
  h[(size_t)(n0 + 1) * DH + j] = acc1;
  h[(size_t)(n0 + 2) * DH + j] = acc2;
  h[(size_t)(n0 + 3) * DH + j] = acc3;
}

// ---------------------------------------------------------------------------
// BN column stats.
// ---------------------------------------------------------------------------
__global__ __launch_bounds__(256) void bn_stats_kernel(const float* __restrict__ h,
                                                       float* __restrict__ sums,
                                                       float* __restrict__ sumsq) {
  int tid = blockIdx.x * 256 + threadIdx.x;
  int c = tid & (DH - 1);
  int r = tid >> 7;
  int stride = (gridDim.x * 256) >> 7;
  float sv = 0.0f, qv = 0.0f;
  for (; r < NN; r += stride) {
    float v = h[(size_t)r * DH + c];
    sv += v;
    qv += v * v;
  }
  atomicAdd(&sums[c], sv);
  atomicAdd(&sumsq[c], qv);
}

__global__ __launch_bounds__(256) void bn_apply_kernel(float* __restrict__ h,
                                                       const float* __restrict__ sums,
                                                       const float* __restrict__ sumsq,
                                                       const float* __restrict__ gamma,
                                                       const float* __restrict__ beta) {
  int tid = blockIdx.x * 256 + threadIdx.x;
  int c = tid & (DH - 1);
  float mean = sums[c] * (1.0f / NN);
  float var = sumsq[c] * (1.0f / NN) - mean * mean;
  float scl = gamma[c] * rsqrtf(var + 1e-5f);
  float sh = beta[c] - mean * scl;
  float v = h[tid] * scl + sh;
  h[tid] = fmaxf(v, 0.0f);
}

// ---------------------------------------------------------------------------
// Layer 2 + fused log_softmax (s pre-normalized).
// ---------------------------------------------------------------------------
__global__ __launch_bounds__(64) void gemm2_kernel(const float* __restrict__ s,
                                                   const float* __restrict__ h,
                                                   const float* __restrict__ W2l,
                                                   const float* __restrict__ b2l,
                                                   const float* __restrict__ W2r,
                                                   float* __restrict__ out) {
  __shared__ float sA[4][DH];
  __shared__ float sH[4][DH];
  int n0 = blockIdx.x * 4;
  int j = threadIdx.x;  // 0..63
#pragma unroll
  for (int n = 0; n < 4; n++) {
    sA[n][j] = s[(size_t)(n0 + n) * DH + j];
    sA[n][j + 64] = s[(size_t)(n0 + n) * DH + j + 64];
    sH[n][j] = h[(size_t)(n0 + n) * DH + j];
    sH[n][j + 64] = h[(size_t)(n0 + n) * DH + j + 64];
  }
  __syncthreads();
  float acc[4];
  float b = b2l[j];
  acc[0] = acc[1] = acc[2] = acc[3] = b;
  const float4* wl4 = (const float4*)(W2l + (size_t)j * DH);
  const float4* wr4 = (const float4*)(W2r + (size_t)j * DH);
#pragma unroll 8
  for (int k = 0; k < DH / 4; k++) {
    float4 wl = wl4[k];
    float4 wr = wr4[k];
#pragma unroll
    for (int n = 0; n < 4; n++) {
      float4 a = ((const float4*)sA[n])[k];
      float4 hh = ((const float4*)sH[n])[k];
      acc[n] += a.x * wl.x + a.y * wl.y + a.z * wl.z + a.w * wl.w
              + hh.x * wr.x + hh.y * wr.y + hh.z * wr.z + hh.w * wr.w;
    }
  }
#pragma unroll
  for (int n = 0; n < 4; n++) {
    float m = acc[n];
    for (int o = 32; o > 0; o >>= 1) m = fmaxf(m, __shfl_xor(m, o, 64));
    float ev = __expf(acc[n] - m);
    float ssum = ev;
    for (int o = 32; o > 0; o >>= 1) ssum += __shfl_xor(ssum, o, 64);
    out[(size_t)(n0 + n) * DOUT + j] = acc[n] - m - logf(ssum);
  }
}

// ---------------------------------------------------------------------------
extern "C" void kernel_launch(void* const* d_in, const int* in_sizes, int n_in,
                              void* d_out, int out_size, void* d_ws, size_t ws_size,
                              hipStream_t stream) {
  const float* x = (const float*)d_in[0];
  const int* ei = (const int*)d_in[1];
  const float* W1l = (const float*)d_in[2];
  const float* b1l = (const float*)d_in[3];
  const float* W1r = (const float*)d_in[4];
  const float* gamma = (const float*)d_in[5];
  const float* beta = (const float*)d_in[6];
  const float* W2l = (const float*)d_in[7];
  const float* b2l = (const float*)d_in[8];
  const float* W2r = (const float*)d_in[9];
  float* out = (float*)d_out;
  int E = in_sizes[1] / 2;

  // workspace (floats/ints): s_buf[N*128] | h_buf[N*128] | degi[N] | row_ptr[N]
  //                          | col[E] | sums[128] | sumsq[128] | flag  (~110 MB)
  float* s_buf = (float*)d_ws;
  float* h_buf = s_buf + (size_t)NN * DH;
  int* degi = (int*)(h_buf + (size_t)NN * DH);
  int* row_ptr = degi + NN;
  int* col = row_ptr + NN;
  float* sums = (float*)(col + E);
  float* sumsq = sums + DH;
  int* flag = (int*)(sumsq + DH);

  hipMemsetAsync(degi, 0, NN * sizeof(int), stream);
  hipMemsetAsync(sums, 0, 2 * DH * sizeof(float), stream);

  detect_kernel<<<1, 256, 0, stream>>>(ei, E, flag);
  deg_kernel<<<(E + 255) / 256, 256, 0, stream>>>(ei, E, flag, degi);
  scan_kernel<<<1, 1024, 0, stream>>>(degi, row_ptr);
  fill_kernel<<<(E + 255) / 256, 256, 0, stream>>>(ei, E, flag, row_ptr, col);
  gather_kernel<<<(NN * 32 + 255) / 256, 256, 0, stream>>>(x, col, row_ptr, degi, s_buf);
  gemm1_kernel<<<NN / 4, 128, 0, stream>>>(s_buf, x, W1l, b1l, W1r, h_buf);
  bn_stats_kernel<<<512, 256, 0, stream>>>(h_buf, sums, sumsq);
  bn_apply_kernel<<<(NN * DH) / 256, 256, 0, stream>>>(h_buf, sums, sumsq, gamma, beta);
  gather_kernel<<<(NN * 32 + 255) / 256, 256, 0, stream>>>(h_buf, col, row_ptr, degi, s_buf);
  gemm2_kernel<<<NN / 4, 64, 0, stream>>>(s_buf, h_buf, W2l, b2l, W2r, out);
}

// Round 3
// 791.713 us; speedup vs baseline: 7.8435x; 1.5339x over previous
//
#include <hip/hip_runtime.h>
#include <math.h>

#define NN 100000
#define DH 128
#define DOUT 64

typedef __attribute__((ext_vector_type(8))) short bf16x8;
typedef __attribute__((ext_vector_type(4))) float f32x4;

__device__ __forceinline__ short f2bf(float f) {
  unsigned u = __float_as_uint(f);
  unsigned r = (u + 0x7fffu + ((u >> 16) & 1u)) >> 16;
  return (short)r;
}

// ---------------------------------------------------------------------------
// Edge-index dtype detector (int64 reference vs int32 harness doc).
// ---------------------------------------------------------------------------
__global__ __launch_bounds__(256) void detect_kernel(const int* __restrict__ ei, int E,
                                                     int* __restrict__ flag) {
  const long long* e64 = (const long long*)ei;
  int lim = E < 1024 ? E : 1024;
  int ok = 1;
  for (int i = threadIdx.x; i < lim; i += 256) {
    long long v = e64[i];
    if (v < 0 || v >= NN) ok = 0;
  }
  __shared__ int s_ok;
  if (threadIdx.x == 0) s_ok = 1;
  __syncthreads();
  if (!ok) atomicAnd(&s_ok, 0);
  __syncthreads();
  if (threadIdx.x == 0) *flag = s_ok;
}

__device__ __forceinline__ int edge_at(const int* __restrict__ ei, int is64, size_t pos) {
  return is64 ? (int)(((const long long*)ei)[pos]) : ei[pos];
}

// ---------------------------------------------------------------------------
// In-degree histogram (int atomics).
// ---------------------------------------------------------------------------
__global__ __launch_bounds__(256) void deg_kernel(const int* __restrict__ ei, int E,
                                                  const int* __restrict__ flag,
                                                  int* __restrict__ degi) {
  int e = blockIdx.x * 256 + threadIdx.x;
  if (e >= E) return;
  int is64 = *flag;
  int dst = edge_at(ei, is64, (size_t)E + e);
  atomicAdd(&degi[dst], 1);
}

// ---------------------------------------------------------------------------
// Exclusive scan of degi -> row_ptr. Single block, 1024 threads, chunked.
// ---------------------------------------------------------------------------
__global__ __launch_bounds__(1024) void scan_kernel(const int* __restrict__ degi,
                                                    int* __restrict__ row_ptr) {
  __shared__ int warp_sums[16];
  __shared__ int s_offset;
  int lane = threadIdx.x & 63;
  int wid = threadIdx.x >> 6;
  if (threadIdx.x == 0) s_offset = 0;
  __syncthreads();
  for (int base = 0; base < NN; base += 1024) {
    int i = base + threadIdx.x;
    int v = (i < NN) ? degi[i] : 0;
    int sv = v;
#pragma unroll
    for (int o = 1; o < 64; o <<= 1) {
      int t = __shfl_up(sv, o, 64);
      if (lane >= o) sv += t;
    }
    if (lane == 63) warp_sums[wid] = sv;
    __syncthreads();
    if (wid == 0 && lane < 16) {
      int ws = warp_sums[lane];
#pragma unroll
      for (int o = 1; o < 16; o <<= 1) {
        int t = __shfl_up(ws, o, 16);
        if (lane >= o) ws += t;
      }
      warp_sums[lane] = ws;
    }
    __syncthreads();
    int wave_off = (wid == 0) ? 0 : warp_sums[wid - 1];
    int excl = s_offset + wave_off + sv - v;
    if (i < NN) row_ptr[i] = excl;
    __syncthreads();
    if (threadIdx.x == 1023) s_offset = excl + v;
    __syncthreads();
  }
}

// ---------------------------------------------------------------------------
// CSR fill. row_ptr doubles as cursor; after: row_ptr[n] == start[n]+deg[n].
// ---------------------------------------------------------------------------
__global__ __launch_bounds__(256) void fill_kernel(const int* __restrict__ ei, int E,
                                                   const int* __restrict__ flag,
                                                   int* __restrict__ row_ptr,
                                                   int* __restrict__ col) {
  int e = blockIdx.x * 256 + threadIdx.x;
  if (e >= E) return;
  int is64 = *flag;
  int src = edge_at(ei, is64, (size_t)e);
  int dst = edge_at(ei, is64, (size_t)E + e);
  int pos = atomicAdd(&row_ptr[dst], 1);
  col[pos] = src;
}

// ---------------------------------------------------------------------------
// Gather-based mean aggregation: 32 lanes per node, float4 per lane.
// ---------------------------------------------------------------------------
__global__ __launch_bounds__(256) void gather_kernel(const float* __restrict__ feat,
                                                     const int* __restrict__ col,
                                                     const int* __restrict__ row_end,
                                                     const int* __restrict__ degi,
                                                     float* __restrict__ outp) {
  int tid = blockIdx.x * 256 + threadIdx.x;
  int n = tid >> 5;
  if (n >= NN) return;
  int g = tid & 31;
  int d = degi[n];
  int start = row_end[n] - d;
  float4 acc = make_float4(0.f, 0.f, 0.f, 0.f);
#pragma unroll 4
  for (int i = 0; i < d; i++) {
    int src = col[start + i];
    float4 v = ((const float4*)(feat + (size_t)src * DH))[g];
    acc.x += v.x; acc.y += v.y; acc.z += v.z; acc.w += v.w;
  }
  float inv = 1.0f / (float)max(d, 1);
  ((float4*)(outp + (size_t)n * DH))[g] =
      make_float4(acc.x * inv, acc.y * inv, acc.z * inv, acc.w * inv);
}

// ---------------------------------------------------------------------------
// Weight conversion: Wb1[128][256] = [W1l | W1r] bf16, Wb2[64][256] likewise.
// ---------------------------------------------------------------------------
__global__ __launch_bounds__(256) void convw_kernel(const float* __restrict__ W1l,
                                                    const float* __restrict__ W1r,
                                                    const float* __restrict__ W2l,
                                                    const float* __restrict__ W2r,
                                                    unsigned short* __restrict__ Wb1,
                                                    unsigned short* __restrict__ Wb2) {
  int tid = blockIdx.x * 256 + threadIdx.x;
  if (tid < 128 * 256) {
    int n = tid >> 8, k = tid & 255;
    float v = (k < 128) ? W1l[n * 128 + k] : W1r[n * 128 + (k - 128)];
    Wb1[tid] = (unsigned short)f2bf(v);
  } else if (tid < 128 * 256 + 64 * 256) {
    int t2 = tid - 128 * 256;
    int n = t2 >> 8, k = t2 & 255;
    float v = (k < 128) ? W2l[n * 128 + k] : W2r[n * 128 + (k - 128)];
    Wb2[t2] = (unsigned short)f2bf(v);
  }
}

// ---------------------------------------------------------------------------
// Layer 1 MFMA GEMM: h[row][col] = b[col] + sum_k A[row][k]*Wb1[col][k]
// A = [s | x] (K=256, converted to bf16 on the fly). 256 thr = 4 waves,
// wave handles 16 rows x 128 cols via 8 col-tiles of 16x16x32 MFMA.
// ---------------------------------------------------------------------------
__global__ __launch_bounds__(256) void gemm1_mfma(const float* __restrict__ s,
                                                  const float* __restrict__ x,
                                                  const unsigned short* __restrict__ Wb,
                                                  const float* __restrict__ b1l,
                                                  float* __restrict__ h) {
  int w = threadIdx.x >> 6;
  int l = threadIdx.x & 63;
  int rowbase = blockIdx.x * 64 + w * 16;
  int m = l & 15;
  int q = l >> 4;  // quad 0..3
  int row = rowbase + m;
  int rl = row < NN ? row : NN - 1;
  f32x4 acc[8];
#pragma unroll
  for (int t = 0; t < 8; t++) acc[t] = (f32x4){0.f, 0.f, 0.f, 0.f};
#pragma unroll
  for (int ks = 0; ks < 8; ks++) {
    const float* src = (ks < 4) ? (s + (size_t)rl * DH + ks * 32 + q * 8)
                                : (x + (size_t)rl * DH + (ks - 4) * 32 + q * 8);
    float4 f0 = ((const float4*)src)[0];
    float4 f1 = ((const float4*)src)[1];
    bf16x8 af;
    af[0] = f2bf(f0.x); af[1] = f2bf(f0.y); af[2] = f2bf(f0.z); af[3] = f2bf(f0.w);
    af[4] = f2bf(f1.x); af[5] = f2bf(f1.y); af[6] = f2bf(f1.z); af[7] = f2bf(f1.w);
#pragma unroll
    for (int t = 0; t < 8; t++) {
      const unsigned short* bp = Wb + (size_t)(t * 16 + m) * 256 + ks * 32 + q * 8;
      bf16x8 bf = *(const bf16x8*)bp;
      acc[t] = __builtin_amdgcn_mfma_f32_16x16x32_bf16(af, bf, acc[t], 0, 0, 0);
    }
  }
  // C layout: col = t*16 + m, row = rowbase + q*4 + r
#pragma unroll
  for (int t = 0; t < 8; t++) {
    float bias = b1l[t * 16 + m];
#pragma unroll
    for (int r = 0; r < 4; r++) {
      int rr = rowbase + q * 4 + r;
      if (rr < NN) h[(size_t)rr * DH + t * 16 + m] = acc[t][r] + bias;
    }
  }
}

// ---------------------------------------------------------------------------
// Layer 2 MFMA GEMM + fused log_softmax. A = [s2 | h], N=64 (4 col-tiles).
// ---------------------------------------------------------------------------
__global__ __launch_bounds__(256) void gemm2_mfma(const float* __restrict__ s,
                                                  const float* __restrict__ hin,
                                                  const unsigned short* __restrict__ Wb,
                                                  const float* __restrict__ b2l,
                                                  float* __restrict__ out) {
  int w = threadIdx.x >> 6;
  int l = threadIdx.x & 63;
  int rowbase = blockIdx.x * 64 + w * 16;
  int m = l & 15;
  int q = l >> 4;
  int row = rowbase + m;
  int rl = row < NN ? row : NN - 1;
  f32x4 acc[4];
#pragma unroll
  for (int t = 0; t < 4; t++) acc[t] = (f32x4){0.f, 0.f, 0.f, 0.f};
#pragma unroll
  for (int ks = 0; ks < 8; ks++) {
    const float* src = (ks < 4) ? (s + (size_t)rl * DH + ks * 32 + q * 8)
                                : (hin + (size_t)rl * DH + (ks - 4) * 32 + q * 8);
    float4 f0 = ((const float4*)src)[0];
    float4 f1 = ((const float4*)src)[1];
    bf16x8 af;
    af[0] = f2bf(f0.x); af[1] = f2bf(f0.y); af[2] = f2bf(f0.z); af[3] = f2bf(f0.w);
    af[4] = f2bf(f1.x); af[5] = f2bf(f1.y); af[6] = f2bf(f1.z); af[7] = f2bf(f1.w);
#pragma unroll
    for (int t = 0; t < 4; t++) {
      const unsigned short* bp = Wb + (size_t)(t * 16 + m) * 256 + ks * 32 + q * 8;
      bf16x8 bf = *(const bf16x8*)bp;
      acc[t] = __builtin_amdgcn_mfma_f32_16x16x32_bf16(af, bf, acc[t], 0, 0, 0);
    }
  }
  float v[4][4];
#pragma unroll
  for (int t = 0; t < 4; t++) {
    float bias = b2l[t * 16 + m];
#pragma unroll
    for (int r = 0; r < 4; r++) v[t][r] = acc[t][r] + bias;
  }
  // log_softmax per output row: row = rowbase + q*4 + r, cols spread over
  // in-lane t (4) and the 16-lane m-group (xor shuffles 1,2,4,8 stay in-group)
#pragma unroll
  for (int r = 0; r < 4; r++) {
    float mx = fmaxf(fmaxf(v[0][r], v[1][r]), fmaxf(v[2][r], v[3][r]));
    mx = fmaxf(mx, __shfl_xor(mx, 1, 64));
    mx = fmaxf(mx, __shfl_xor(mx, 2, 64));
    mx = fmaxf(mx, __shfl_xor(mx, 4, 64));
    mx = fmaxf(mx, __shfl_xor(mx, 8, 64));
    float se = __expf(v[0][r] - mx) + __expf(v[1][r] - mx) +
               __expf(v[2][r] - mx) + __expf(v[3][r] - mx);
    se += __shfl_xor(se, 1, 64);
    se += __shfl_xor(se, 2, 64);
    se += __shfl_xor(se, 4, 64);
    se += __shfl_xor(se, 8, 64);
    float lse = mx + logf(se);
    int rr = rowbase + q * 4 + r;
    if (rr < NN) {
#pragma unroll
      for (int t = 0; t < 4; t++)
        out[(size_t)rr * DOUT + t * 16 + m] = v[t][r] - lse;
    }
  }
}

// ---------------------------------------------------------------------------
// BN column stats + apply (unchanged).
// ---------------------------------------------------------------------------
__global__ __launch_bounds__(256) void bn_stats_kernel(const float* __restrict__ h,
                                                       float* __restrict__ sums,
                                                       float* __restrict__ sumsq) {
  int tid = blockIdx.x * 256 + threadIdx.x;
  int c = tid & (DH - 1);
  int r = tid >> 7;
  int stride = (gridDim.x * 256) >> 7;
  float sv = 0.0f, qv = 0.0f;
  for (; r < NN; r += stride) {
    float v = h[(size_t)r * DH + c];
    sv += v;
    qv += v * v;
  }
  atomicAdd(&sums[c], sv);
  atomicAdd(&sumsq[c], qv);
}

__global__ __launch_bounds__(256) void bn_apply_kernel(float* __restrict__ h,
                                                       const float* __restrict__ sums,
                                                       const float* __restrict__ sumsq,
                                                       const float* __restrict__ gamma,
                                                       const float* __restrict__ beta) {
  int tid = blockIdx.x * 256 + threadIdx.x;
  int c = tid & (DH - 1);
  float mean = sums[c] * (1.0f / NN);
  float var = sumsq[c] * (1.0f / NN) - mean * mean;
  float scl = gamma[c] * rsqrtf(var + 1e-5f);
  float sh = beta[c] - mean * scl;
  float v = h[tid] * scl + sh;
  h[tid] = fmaxf(v, 0.0f);
}

// ---------------------------------------------------------------------------
extern "C" void kernel_launch(void* const* d_in, const int* in_sizes, int n_in,
                              void* d_out, int out_size, void* d_ws, size_t ws_size,
                              hipStream_t stream) {
  const float* x = (const float*)d_in[0];
  const int* ei = (const int*)d_in[1];
  const float* W1l = (const float*)d_in[2];
  const float* b1l = (const float*)d_in[3];
  const float* W1r = (const float*)d_in[4];
  const float* gamma = (const float*)d_in[5];
  const float* beta = (const float*)d_in[6];
  const float* W2l = (const float*)d_in[7];
  const float* b2l = (const float*)d_in[8];
  const float* W2r = (const float*)d_in[9];
  float* out = (float*)d_out;
  int E = in_sizes[1] / 2;

  // workspace: s_buf[N*128] | h_buf[N*128] | degi[N] | row_ptr[N] | col[E]
  //            | sums[128] | sumsq[128] | flag[1] | Wb1[128*256] | Wb2[64*256]
  float* s_buf = (float*)d_ws;
  float* h_buf = s_buf + (size_t)NN * DH;
  int* degi = (int*)(h_buf + (size_t)NN * DH);
  int* row_ptr = degi + NN;
  int* col = row_ptr + NN;
  float* sums = (float*)(col + E);
  float* sumsq = sums + DH;
  int* flag = (int*)(sumsq + DH);
  unsigned short* Wb1 = (unsigned short*)(flag + 1);
  unsigned short* Wb2 = Wb1 + 128 * 256;

  hipMemsetAsync(degi, 0, NN * sizeof(int), stream);
  hipMemsetAsync(sums, 0, 2 * DH * sizeof(float), stream);

  detect_kernel<<<1, 256, 0, stream>>>(ei, E, flag);
  convw_kernel<<<192, 256, 0, stream>>>(W1l, W1r, W2l, W2r, Wb1, Wb2);
  deg_kernel<<<(E + 255) / 256, 256, 0, stream>>>(ei, E, flag, degi);
  scan_kernel<<<1, 1024, 0, stream>>>(degi, row_ptr);
  fill_kernel<<<(E + 255) / 256, 256, 0, stream>>>(ei, E, flag, row_ptr, col);
  gather_kernel<<<(NN * 32 + 255) / 256, 256, 0, stream>>>(x, col, row_ptr, degi, s_buf);
  gemm1_mfma<<<(NN + 63) / 64, 256, 0, stream>>>(s_buf, x, Wb1, b1l, h_buf);
  bn_stats_kernel<<<512, 256, 0, stream>>>(h_buf, sums, sumsq);
  bn_apply_kernel<<<(NN * DH) / 256, 256, 0, stream>>>(h_buf, sums, sumsq, gamma, beta);
  gather_kernel<<<(NN * 32 + 255) / 256, 256, 0, stream>>>(h_buf, col, row_ptr, degi, s_buf);
  gemm2_mfma<<<(NN + 63) / 64, 256, 0, stream>>>(s_buf, h_buf, Wb2, b2l, out);
}